// Round 1
// baseline (10778.201 us; speedup 1.0000x reference)
//
#include <hip/hip_runtime.h>
#include <cstdint>
#include <cstddef>

#define BATCH   65536
#define RANK_K  32769   // sorted_desc[32768] == 32769-th largest (1-indexed)

// direct global->LDS async copy, 16B per lane (dest = wave-uniform base + lane*16)
__device__ __forceinline__ void glds16(const float* gsrc, float* ldst)
{
    __builtin_amdgcn_global_load_lds(
        (const __attribute__((address_space(1))) void*)gsrc,
        (__attribute__((address_space(3))) void*)ldst,
        16, 0, 0);
}

// ============ big GEMM (layers 1&2): C = relu((A*rowmask) @ B + bias), + per-row sum-of-squares partials ============
// BM=256, BN=128, BK=16, 256 threads, 16x8 per thread.
// v2: double-buffered LDS, one barrier per K-tile (T3 minimum 2-phase):
//   - B staged via global_load_lds width=16, with a 2-way-free XOR bank swizzle
//     (source column pre-swizzled since glds writes linearly; read applies the
//     same involution  granule ^= (granule>>4)&1  -> all bank-quads 2-way = free)
//   - A staged via register prefetch (transpose requires the reg round-trip);
//     vmcnt wait naturally sinks to the ds_write at the bottom of the tile.
// Per-output-element FMA chain order is IDENTICAL to the validated kernel
// (k ascending, single-register chain, bias->relu->square->16-group row
// reduction in same order) -> bit-identical results -> masks cannot flip.
template<bool MASKED>
__global__ __launch_bounds__(256, 2)
void gemm_relu_norm(const float* __restrict__ A, const float* __restrict__ B,
                    const float* __restrict__ bias, const float* __restrict__ mask,
                    float* __restrict__ C, float* __restrict__ normPart,
                    const int N, const int K)
{
    __shared__ float As[2][16][260];   // [buf][k][row], padded (row-stride 1040B, 16B aligned)
    __shared__ float Bs[2][16][128];   // [buf][k][col], UNPADDED (glds dest must be linear)

    const int t    = threadIdx.x;
    const int tr   = t >> 4;          // 0..15 row group (16 rows each)
    const int tc   = t & 15;          // 0..15 col group (8 cols each)
    const int row0 = blockIdx.x * 256;
    const int col0 = blockIdx.y * 128;

    // A-load: thread t loads row (row0+t), 16 consecutive k per tile
    const float* Aptr = A + (size_t)(row0 + t) * K;

    // B glds mapping: thread t owns dest granule t (k=t>>5, gc=t&31) and granule 256+t (k+8, same gc).
    // Stored data at granule gc comes from source column 4*(gc ^ ((gc>>4)&1)).
    const int gc  = t & 31;
    const int csw = 4 * (gc ^ ((gc >> 4) & 1));
    const float* BsrcBase = B + (size_t)(t >> 5) * N + col0 + csw;
    float* ldsB0 = &Bs[0][0][0] + (t >> 6) * 256;   // wave-uniform LDS bases
    float* ldsB1 = &Bs[1][0][0] + (t >> 6) * 256;

    // swizzled B read offsets (involution matches the store side)
    const int bsw   = ((tc >> 3) & 1) << 2;         // 0 or 4 floats
    const int bo_lo = (tc * 8) ^ bsw;               // holds cols tc*8   .. +3
    const int bo_hi = (tc * 8 + 4) ^ bsw;           // holds cols tc*8+4 .. +7

    float scale = 1.0f;
    if (MASKED) scale = mask[row0 + t];

    float acc[16][8];
    #pragma unroll
    for (int i = 0; i < 16; ++i)
        #pragma unroll
        for (int j = 0; j < 8; ++j) acc[i][j] = 0.0f;

    const int T = K >> 4;

    // ---- prologue: stage tile 0 into buffer 0 ----
    {
        glds16(BsrcBase, ldsB0);
        glds16(BsrcBase + (size_t)8 * N, ldsB0 + 1024);
        float4 a0 = *(const float4*)(Aptr + 0);
        float4 a1 = *(const float4*)(Aptr + 4);
        float4 a2 = *(const float4*)(Aptr + 8);
        float4 a3 = *(const float4*)(Aptr + 12);
        if (MASKED) {
            a0.x *= scale; a0.y *= scale; a0.z *= scale; a0.w *= scale;
            a1.x *= scale; a1.y *= scale; a1.z *= scale; a1.w *= scale;
            a2.x *= scale; a2.y *= scale; a2.z *= scale; a2.w *= scale;
            a3.x *= scale; a3.y *= scale; a3.z *= scale; a3.w *= scale;
        }
        As[0][ 0][t] = a0.x; As[0][ 1][t] = a0.y; As[0][ 2][t] = a0.z; As[0][ 3][t] = a0.w;
        As[0][ 4][t] = a1.x; As[0][ 5][t] = a1.y; As[0][ 6][t] = a1.z; As[0][ 7][t] = a1.w;
        As[0][ 8][t] = a2.x; As[0][ 9][t] = a2.y; As[0][10][t] = a2.z; As[0][11][t] = a2.w;
        As[0][12][t] = a3.x; As[0][13][t] = a3.y; As[0][14][t] = a3.z; As[0][15][t] = a3.w;
    }
    __syncthreads();   // compiler emits vmcnt(0) lgkmcnt(0) drain here

    int cur = 0;
    for (int tile = 0; tile < T; ++tile, cur ^= 1) {
        float4 a0, a1, a2, a3;
        const bool pf = (tile + 1 < T);
        if (pf) {
            // issue next-tile stage FIRST (in flight across the whole compute phase)
            const size_t k0n = (size_t)(tile + 1) * 16;
            const float* bs = BsrcBase + k0n * N;
            float* ldsB = cur ? ldsB0 : ldsB1;          // next buffer
            glds16(bs, ldsB);
            glds16(bs + (size_t)8 * N, ldsB + 1024);
            a0 = *(const float4*)(Aptr + k0n);
            a1 = *(const float4*)(Aptr + k0n + 4);
            a2 = *(const float4*)(Aptr + k0n + 8);
            a3 = *(const float4*)(Aptr + k0n + 12);
        }

        #pragma unroll
        for (int kk = 0; kk < 16; ++kk) {
            float a_[16], b_[8];
            *(float4*)&a_[0]  = *(const float4*)&As[cur][kk][tr*16];
            *(float4*)&a_[4]  = *(const float4*)&As[cur][kk][tr*16 + 4];
            *(float4*)&a_[8]  = *(const float4*)&As[cur][kk][tr*16 + 8];
            *(float4*)&a_[12] = *(const float4*)&As[cur][kk][tr*16 + 12];
            *(float4*)&b_[0]  = *(const float4*)&Bs[cur][kk][bo_lo];
            *(float4*)&b_[4]  = *(const float4*)&Bs[cur][kk][bo_hi];
            #pragma unroll
            for (int i = 0; i < 16; ++i)
                #pragma unroll
                for (int j = 0; j < 8; ++j)
                    acc[i][j] = fmaf(a_[i], b_[j], acc[i][j]);
        }

        if (pf) {
            // scaling here (not at issue point) so the vmcnt wait lands AFTER compute
            if (MASKED) {
                a0.x *= scale; a0.y *= scale; a0.z *= scale; a0.w *= scale;
                a1.x *= scale; a1.y *= scale; a1.z *= scale; a1.w *= scale;
                a2.x *= scale; a2.y *= scale; a2.z *= scale; a2.w *= scale;
                a3.x *= scale; a3.y *= scale; a3.z *= scale; a3.w *= scale;
            }
            const int nxt = cur ^ 1;
            As[nxt][ 0][t] = a0.x; As[nxt][ 1][t] = a0.y; As[nxt][ 2][t] = a0.z; As[nxt][ 3][t] = a0.w;
            As[nxt][ 4][t] = a1.x; As[nxt][ 5][t] = a1.y; As[nxt][ 6][t] = a1.z; As[nxt][ 7][t] = a1.w;
            As[nxt][ 8][t] = a2.x; As[nxt][ 9][t] = a2.y; As[nxt][10][t] = a2.z; As[nxt][11][t] = a2.w;
            As[nxt][12][t] = a3.x; As[nxt][13][t] = a3.y; As[nxt][14][t] = a3.z; As[nxt][15][t] = a3.w;
        }
        __syncthreads();   // single barrier per tile; drains this tile's glds + A ds_writes
    }

    float bv[8];
    #pragma unroll
    for (int j = 0; j < 8; ++j) bv[j] = bias[col0 + tc*8 + j];

    float rowsum[16];
    #pragma unroll
    for (int i = 0; i < 16; ++i) {
        float s = 0.0f;
        #pragma unroll
        for (int j = 0; j < 8; ++j) {
            float v = fmaxf(acc[i][j] + bv[j], 0.0f);   // dot, +bias, relu (matches ref)
            acc[i][j] = v;
            s = fmaf(v, v, s);
        }
        rowsum[i] = s;
    }

    #pragma unroll
    for (int i = 0; i < 16; ++i) {
        const size_t row = (size_t)(row0 + tr*16 + i);
        *(float4*)&C[row * N + col0 + tc*8]     = *(float4*)&acc[i][0];
        *(float4*)&C[row * N + col0 + tc*8 + 4] = *(float4*)&acc[i][4];
    }

    // red aliases the (now dead) A double-buffer: 256*17*4 = 17408 B <= 33280 B
    float (*red)[17] = (float (*)[17])(&As[0][0][0]);
    #pragma unroll
    for (int i = 0; i < 16; ++i) red[tr*16 + i][tc] = rowsum[i];
    __syncthreads();
    {
        float s = 0.0f;
        #pragma unroll
        for (int x = 0; x < 16; ++x) s += red[t][x];    // fixed order -> deterministic
        normPart[(size_t)blockIdx.y * BATCH + row0 + t] = s;
    }
}

// ============ deterministic partial-sum -> norm (sqrt in double = correctly-rounded fp32 sqrt) ============
__global__ __launch_bounds__(256)
void reduce_norms_kernel(const float* __restrict__ part, float* __restrict__ norms, const int nPart)
{
    const int i = blockIdx.x * 256 + threadIdx.x;
    float s = 0.0f;
    for (int p = 0; p < nPart; ++p) s += part[(size_t)p * BATCH + i];
    norms[i] = (float)sqrt((double)s);
}

// ============ exact 32769-th-largest via binary search on uint key space (no atomics) ============
__global__ __launch_bounds__(1024)
void select_kernel(const float* __restrict__ norms, float* __restrict__ maskOut,
                   float* __restrict__ thrOut)
{
    __shared__ int wsum[16];

    const int t = threadIdx.x;
    unsigned key[64];
    const float4* n4 = (const float4*)norms;
    #pragma unroll
    for (int i = 0; i < 16; ++i) {
        float4 v = n4[i * 1024 + t];
        key[i*4+0] = __float_as_uint(v.x);
        key[i*4+1] = __float_as_uint(v.y);
        key[i*4+2] = __float_as_uint(v.z);
        key[i*4+3] = __float_as_uint(v.w);      // nonneg floats -> monotone uint order
    }

    // V = min{ T : count(key > T) < RANK_K }  == exact RANK_K-th largest value
    unsigned lo = 0u, hi = 0x7F800000u;
    while (lo < hi) {                            // uniform across all threads
        const unsigned mid = lo + ((hi - lo) >> 1);
        int c = 0;
        #pragma unroll
        for (int i = 0; i < 64; ++i) c += (key[i] > mid) ? 1 : 0;
        #pragma unroll
        for (int off = 32; off > 0; off >>= 1) c += __shfl_down(c, off, 64);
        if ((t & 63) == 0) wsum[t >> 6] = c;
        __syncthreads();
        int total = 0;
        #pragma unroll
        for (int w = 0; w < 16; ++w) total += wsum[w];
        if (total < RANK_K) hi = mid; else lo = mid + 1;
        __syncthreads();
    }

    if (t == 0) thrOut[0] = __uint_as_float(lo);
    float4* m4 = (float4*)maskOut;
    #pragma unroll
    for (int i = 0; i < 16; ++i) {
        float4 m;
        m.x = (key[i*4+0] > lo) ? 1.0f : 0.0f;
        m.y = (key[i*4+1] > lo) ? 1.0f : 0.0f;
        m.z = (key[i*4+2] > lo) ? 1.0f : 0.0f;
        m.w = (key[i*4+3] > lo) ? 1.0f : 0.0f;   // strict > like reference
        m4[i * 1024 + t] = m;
    }
}

// ============ layer 3: h3 = relu((h2*m2) @ W3[256x10] + b3), full row norms ============
__global__ __launch_bounds__(256)
void layer3_kernel(const float* __restrict__ h2, const float* __restrict__ W3,
                   const float* __restrict__ b3, const float* __restrict__ mask2,
                   float* __restrict__ h3, float* __restrict__ norms3)
{
    __shared__ float wT[10][260];   // transposed W3 for b128 broadcast reads
    __shared__ float red[64][5];

    const int t    = threadIdx.x;
    const int r    = t & 63;
    const int g    = t >> 6;          // 0..3 column groups (3,3,3,1)
    const int j0   = g * 3;
    const int nj   = (g == 3) ? 1 : 3;
    const int row0 = blockIdx.x * 64;
    const int row  = row0 + r;

    for (int e = t; e < 2560; e += 256) wT[e % 10][e / 10] = W3[e];
    __syncthreads();

    const float m = mask2[row];
    const float* hrow = h2 + (size_t)row * 256;

    float acc[3] = {0.0f, 0.0f, 0.0f};
    for (int k = 0; k < 256; k += 4) {
        float4 v = *(const float4*)(hrow + k);
        v.x *= m; v.y *= m; v.z *= m; v.w *= m;
        float4 w0 = *(const float4*)&wT[j0][k];
        acc[0] += v.x*w0.x + v.y*w0.y + v.z*w0.z + v.w*w0.w;
        if (nj > 1) {
            float4 w1 = *(const float4*)&wT[j0+1][k];
            acc[1] += v.x*w1.x + v.y*w1.y + v.z*w1.z + v.w*w1.w;
            float4 w2 = *(const float4*)&wT[j0+2][k];
            acc[2] += v.x*w2.x + v.y*w2.y + v.z*w2.z + v.w*w2.w;
        }
    }

    float ss = 0.0f;
    for (int jj = 0; jj < nj; ++jj) {
        float v = fmaxf(acc[jj] + b3[j0 + jj], 0.0f);
        h3[(size_t)row * 10 + j0 + jj] = v;
        ss += v * v;
    }
    red[r][g] = ss;
    __syncthreads();
    if (t < 64) {
        float s = red[t][0] + red[t][1] + red[t][2] + red[t][3];  // fixed order
        norms3[row0 + t] = (float)sqrt((double)s);
    }
}

// ============ layer 4: h4 = (h3*m3) @ W4[10x10] + b4 (no relu), norms ============
__global__ __launch_bounds__(256)
void layer4_kernel(const float* __restrict__ h3, const float* __restrict__ W4,
                   const float* __restrict__ b4, const float* __restrict__ mask3,
                   float* __restrict__ h4, float* __restrict__ norms4)
{
    __shared__ float w[100];
    __shared__ float bb[10];
    const int t = threadIdx.x;
    if (t < 100) w[t] = W4[t];
    if (t < 10)  bb[t] = b4[t];
    __syncthreads();

    const int row = blockIdx.x * 256 + t;
    const float m = mask3[row];
    const float* hr = h3 + (size_t)row * 10;
    float v[10];
    #pragma unroll
    for (int k = 0; k < 10; ++k) v[k] = hr[k] * m;

    float s = 0.0f;
    #pragma unroll
    for (int j = 0; j < 10; ++j) {
        float a = 0.0f;
        #pragma unroll
        for (int k = 0; k < 10; ++k) a = fmaf(v[k], w[k*10 + j], a);
        a += bb[j];                     // dot then +bias (matches ref)
        h4[(size_t)row * 10 + j] = a;
        s = fmaf(a, a, s);
    }
    norms4[row] = (float)sqrt((double)s);
}

// ============ final: out = softmax(h4 * m4) ============
__global__ __launch_bounds__(256)
void softmax_kernel(const float* __restrict__ h4, const float* __restrict__ mask4,
                    float* __restrict__ out)
{
    const int t   = threadIdx.x;
    const int row = blockIdx.x * 256 + t;
    const float m = mask4[row];
    const float* hr = h4 + (size_t)row * 10;
    float v[10];
    #pragma unroll
    for (int k = 0; k < 10; ++k) v[k] = hr[k] * m;
    float mx = v[0];
    #pragma unroll
    for (int k = 1; k < 10; ++k) mx = fmaxf(mx, v[k]);
    float e[10];
    float s = 0.0f;
    #pragma unroll
    for (int k = 0; k < 10; ++k) { e[k] = expf(v[k] - mx); s += e[k]; }
    const float inv = 1.0f / s;
    #pragma unroll
    for (int k = 0; k < 10; ++k) out[(size_t)row * 10 + k] = e[k] * inv;
}

extern "C" void kernel_launch(void* const* d_in, const int* in_sizes, int n_in,
                              void* d_out, int out_size, void* d_ws, size_t ws_size,
                              hipStream_t stream)
{
    const float* x  = (const float*)d_in[0];
    const float* W1 = (const float*)d_in[1];
    const float* b1 = (const float*)d_in[2];
    const float* W2 = (const float*)d_in[3];
    const float* b2 = (const float*)d_in[4];
    const float* W3 = (const float*)d_in[5];
    const float* b3 = (const float*)d_in[6];
    const float* W4 = (const float*)d_in[7];
    const float* b4 = (const float*)d_in[8];

    float* out = (float*)d_out;                 // [65536,10]
    float* m1  = out + (size_t)BATCH * 10;      // [65536] each
    float* m2  = m1 + BATCH;
    float* m3  = m2 + BATCH;
    float* m4  = m3 + BATCH;

    float* ws    = (float*)d_ws;
    float* h1    = ws;                                  // 65536*512
    float* h2    = h1 + (size_t)BATCH * 512;            // 65536*256
    float* h3    = h2 + (size_t)BATCH * 256;            // 65536*10
    float* h4    = h3 + (size_t)BATCH * 10;             // 65536*10
    float* n1    = h4 + (size_t)BATCH * 10;             // 65536 x4
    float* n2    = n1 + BATCH;
    float* n3    = n2 + BATCH;
    float* n4    = n3 + BATCH;
    float* part  = n4 + BATCH;                          // 4*65536
    float* thr   = part + (size_t)4 * BATCH;            // 4

    // layer 1: x[65536,784] @ W1[784,512]
    gemm_relu_norm<false><<<dim3(256, 4), 256, 0, stream>>>(x, W1, b1, nullptr, h1, part, 512, 784);
    reduce_norms_kernel<<<256, 256, 0, stream>>>(part, n1, 4);
    select_kernel<<<1, 1024, 0, stream>>>(n1, m1, thr + 0);

    // layer 2: (h1*m1)[65536,512] @ W2[512,256]
    gemm_relu_norm<true><<<dim3(256, 2), 256, 0, stream>>>(h1, W2, b2, m1, h2, part, 256, 512);
    reduce_norms_kernel<<<256, 256, 0, stream>>>(part, n2, 2);
    select_kernel<<<1, 1024, 0, stream>>>(n2, m2, thr + 1);

    // layer 3: (h2*m2)[65536,256] @ W3[256,10]
    layer3_kernel<<<1024, 256, 0, stream>>>(h2, W3, b3, m2, h3, n3);
    select_kernel<<<1, 1024, 0, stream>>>(n3, m3, thr + 2);

    // layer 4: (h3*m3)[65536,10] @ W4[10,10] (no relu)
    layer4_kernel<<<256, 256, 0, stream>>>(h3, W4, b4, m3, h4, n4);
    select_kernel<<<1, 1024, 0, stream>>>(n4, m4, thr + 3);

    // softmax(h4*m4)
    softmax_kernel<<<256, 256, 0, stream>>>(h4, m4, out);
}

// Round 2
// 1288.584 us; speedup vs baseline: 8.3644x; 8.3644x over previous
//
#include <hip/hip_runtime.h>
#include <cstdint>
#include <cstddef>

#define BATCH   65536
#define RANK_K  32769   // sorted_desc[32768] == 32769-th largest (1-indexed)

// ============ big GEMM (layers 1&2): C = relu((A*rowmask) @ B + bias), + per-row sum-of-squares partials ============
// BM=256, BN=128, BK=16, 256 threads, 16x8 per thread.
// v3 = round-0 structure (single-buffered, ds_write staging, acc in AGPRs)
//      + XOR bank swizzle on Bs (the only change):
//   Bs granule g (16B unit) stored at g ^ ((g>>4)&1)  ==  float4 at col-offset
//   (c ^ sw) with sw = ((tc>>3)&1)<<2.  B-reads then hit all 8 bank-quads with
//   2 distinct addresses each (free, m136) instead of 4 quads x 4-way; B-writes
//   spread 8/quad (b128 minimum) instead of 16/quad on even quads only.
// Per-output-element FMA chain order is IDENTICAL to the validated kernel
// (k ascending, single-register chain, bias->relu->square->16-group row
// reduction in same order) -> bit-identical results -> masks cannot flip.
template<bool MASKED>
__global__ __launch_bounds__(256, 2)
void gemm_relu_norm(const float* __restrict__ A, const float* __restrict__ B,
                    const float* __restrict__ bias, const float* __restrict__ mask,
                    float* __restrict__ C, float* __restrict__ normPart,
                    const int N, const int K)
{
    __shared__ float As[16][260];   // [k][row], padded
    __shared__ float Bs[16][128];   // [k][col], granule-swizzled (see header comment)
    __shared__ float red[256][17];  // row-norm partial reduction

    const int t    = threadIdx.x;
    const int tr   = t >> 4;          // 0..15 row group (16 rows each)
    const int tc   = t & 15;          // 0..15 col group (8 cols each)
    const int row0 = blockIdx.x * 256;
    const int col0 = blockIdx.y * 128;

    // A-load: thread t loads row (row0+t), 16 consecutive k per tile (one 64B line)
    const float* Aptr = A + (size_t)(row0 + t) * K;
    // B-load: 16 k-rows x 128 cols; thread: k=t>>4, cols (t&15)*8..+7
    const int bk = t >> 4;
    const int bc = (t & 15) * 8;
    const float* Bptr = B + (size_t)bk * N + col0 + bc;

    // bank swizzle: XOR bit2 of float-offset (16B granule swap) keyed on bit3 of tc.
    // Same formula on store and load sides -> involution -> correct data.
    const int bsw   = ((tc >> 3) & 1) << 2;   // note: tc == t&15 for both roles here
    const int bo_lo = (tc * 8) ^ bsw;
    const int bo_hi = (tc * 8 + 4) ^ bsw;

    float scale = 1.0f;
    if (MASKED) scale = mask[row0 + t];

    float acc[16][8];
    #pragma unroll
    for (int i = 0; i < 16; ++i)
        #pragma unroll
        for (int j = 0; j < 8; ++j) acc[i][j] = 0.0f;

    for (int k0 = 0; k0 < K; k0 += 16) {
        float4 a0 = *(const float4*)(Aptr + k0);
        float4 a1 = *(const float4*)(Aptr + k0 + 4);
        float4 a2 = *(const float4*)(Aptr + k0 + 8);
        float4 a3 = *(const float4*)(Aptr + k0 + 12);
        float4 b0 = *(const float4*)(Bptr + (size_t)k0 * N);
        float4 b1 = *(const float4*)(Bptr + (size_t)k0 * N + 4);
        if (MASKED) {
            a0.x *= scale; a0.y *= scale; a0.z *= scale; a0.w *= scale;
            a1.x *= scale; a1.y *= scale; a1.z *= scale; a1.w *= scale;
            a2.x *= scale; a2.y *= scale; a2.z *= scale; a2.w *= scale;
            a3.x *= scale; a3.y *= scale; a3.z *= scale; a3.w *= scale;
        }
        As[ 0][t] = a0.x; As[ 1][t] = a0.y; As[ 2][t] = a0.z; As[ 3][t] = a0.w;
        As[ 4][t] = a1.x; As[ 5][t] = a1.y; As[ 6][t] = a1.z; As[ 7][t] = a1.w;
        As[ 8][t] = a2.x; As[ 9][t] = a2.y; As[10][t] = a2.z; As[11][t] = a2.w;
        As[12][t] = a3.x; As[13][t] = a3.y; As[14][t] = a3.z; As[15][t] = a3.w;
        *(float4*)&Bs[bk][bc ^ bsw]       = b0;   // swizzled store (involution with read)
        *(float4*)&Bs[bk][(bc + 4) ^ bsw] = b1;
        __syncthreads();
        #pragma unroll
        for (int kk = 0; kk < 16; ++kk) {
            float a_[16], b_[8];
            *(float4*)&a_[0]  = *(const float4*)&As[kk][tr*16];
            *(float4*)&a_[4]  = *(const float4*)&As[kk][tr*16 + 4];
            *(float4*)&a_[8]  = *(const float4*)&As[kk][tr*16 + 8];
            *(float4*)&a_[12] = *(const float4*)&As[kk][tr*16 + 12];
            *(float4*)&b_[0]  = *(const float4*)&Bs[kk][bo_lo];
            *(float4*)&b_[4]  = *(const float4*)&Bs[kk][bo_hi];
            #pragma unroll
            for (int i = 0; i < 16; ++i)
                #pragma unroll
                for (int j = 0; j < 8; ++j)
                    acc[i][j] = fmaf(a_[i], b_[j], acc[i][j]);
        }
        __syncthreads();
    }

    float bv[8];
    #pragma unroll
    for (int j = 0; j < 8; ++j) bv[j] = bias[col0 + tc*8 + j];

    float rowsum[16];
    #pragma unroll
    for (int i = 0; i < 16; ++i) {
        float s = 0.0f;
        #pragma unroll
        for (int j = 0; j < 8; ++j) {
            float v = fmaxf(acc[i][j] + bv[j], 0.0f);   // dot, +bias, relu (matches ref)
            acc[i][j] = v;
            s = fmaf(v, v, s);
        }
        rowsum[i] = s;
    }

    #pragma unroll
    for (int i = 0; i < 16; ++i) {
        const size_t row = (size_t)(row0 + tr*16 + i);
        *(float4*)&C[row * N + col0 + tc*8]     = *(float4*)&acc[i][0];
        *(float4*)&C[row * N + col0 + tc*8 + 4] = *(float4*)&acc[i][4];
    }

    #pragma unroll
    for (int i = 0; i < 16; ++i) red[tr*16 + i][tc] = rowsum[i];
    __syncthreads();
    {
        float s = 0.0f;
        #pragma unroll
        for (int x = 0; x < 16; ++x) s += red[t][x];    // fixed order -> deterministic
        normPart[(size_t)blockIdx.y * BATCH + row0 + t] = s;
    }
}

// ============ deterministic partial-sum -> norm (sqrt in double = correctly-rounded fp32 sqrt) ============
__global__ __launch_bounds__(256)
void reduce_norms_kernel(const float* __restrict__ part, float* __restrict__ norms, const int nPart)
{
    const int i = blockIdx.x * 256 + threadIdx.x;
    float s = 0.0f;
    for (int p = 0; p < nPart; ++p) s += part[(size_t)p * BATCH + i];
    norms[i] = (float)sqrt((double)s);
}

// ============ exact 32769-th-largest via binary search on uint key space (no atomics) ============
__global__ __launch_bounds__(1024)
void select_kernel(const float* __restrict__ norms, float* __restrict__ maskOut,
                   float* __restrict__ thrOut)
{
    __shared__ int wsum[16];

    const int t = threadIdx.x;
    unsigned key[64];
    const float4* n4 = (const float4*)norms;
    #pragma unroll
    for (int i = 0; i < 16; ++i) {
        float4 v = n4[i * 1024 + t];
        key[i*4+0] = __float_as_uint(v.x);
        key[i*4+1] = __float_as_uint(v.y);
        key[i*4+2] = __float_as_uint(v.z);
        key[i*4+3] = __float_as_uint(v.w);      // nonneg floats -> monotone uint order
    }

    // V = min{ T : count(key > T) < RANK_K }  == exact RANK_K-th largest value
    unsigned lo = 0u, hi = 0x7F800000u;
    while (lo < hi) {                            // uniform across all threads
        const unsigned mid = lo + ((hi - lo) >> 1);
        int c = 0;
        #pragma unroll
        for (int i = 0; i < 64; ++i) c += (key[i] > mid) ? 1 : 0;
        #pragma unroll
        for (int off = 32; off > 0; off >>= 1) c += __shfl_down(c, off, 64);
        if ((t & 63) == 0) wsum[t >> 6] = c;
        __syncthreads();
        int total = 0;
        #pragma unroll
        for (int w = 0; w < 16; ++w) total += wsum[w];
        if (total < RANK_K) hi = mid; else lo = mid + 1;
        __syncthreads();
    }

    if (t == 0) thrOut[0] = __uint_as_float(lo);
    float4* m4 = (float4*)maskOut;
    #pragma unroll
    for (int i = 0; i < 16; ++i) {
        float4 m;
        m.x = (key[i*4+0] > lo) ? 1.0f : 0.0f;
        m.y = (key[i*4+1] > lo) ? 1.0f : 0.0f;
        m.z = (key[i*4+2] > lo) ? 1.0f : 0.0f;
        m.w = (key[i*4+3] > lo) ? 1.0f : 0.0f;   // strict > like reference
        m4[i * 1024 + t] = m;
    }
}

// ============ layer 3: h3 = relu((h2*m2) @ W3[256x10] + b3), full row norms ============
__global__ __launch_bounds__(256)
void layer3_kernel(const float* __restrict__ h2, const float* __restrict__ W3,
                   const float* __restrict__ b3, const float* __restrict__ mask2,
                   float* __restrict__ h3, float* __restrict__ norms3)
{
    __shared__ float wT[10][260];   // transposed W3 for b128 broadcast reads
    __shared__ float red[64][5];

    const int t    = threadIdx.x;
    const int r    = t & 63;
    const int g    = t >> 6;          // 0..3 column groups (3,3,3,1)
    const int j0   = g * 3;
    const int nj   = (g == 3) ? 1 : 3;
    const int row0 = blockIdx.x * 64;
    const int row  = row0 + r;

    for (int e = t; e < 2560; e += 256) wT[e % 10][e / 10] = W3[e];
    __syncthreads();

    const float m = mask2[row];
    const float* hrow = h2 + (size_t)row * 256;

    float acc[3] = {0.0f, 0.0f, 0.0f};
    for (int k = 0; k < 256; k += 4) {
        float4 v = *(const float4*)(hrow + k);
        v.x *= m; v.y *= m; v.z *= m; v.w *= m;
        float4 w0 = *(const float4*)&wT[j0][k];
        acc[0] += v.x*w0.x + v.y*w0.y + v.z*w0.z + v.w*w0.w;
        if (nj > 1) {
            float4 w1 = *(const float4*)&wT[j0+1][k];
            acc[1] += v.x*w1.x + v.y*w1.y + v.z*w1.z + v.w*w1.w;
            float4 w2 = *(const float4*)&wT[j0+2][k];
            acc[2] += v.x*w2.x + v.y*w2.y + v.z*w2.z + v.w*w2.w;
        }
    }

    float ss = 0.0f;
    for (int jj = 0; jj < nj; ++jj) {
        float v = fmaxf(acc[jj] + b3[j0 + jj], 0.0f);
        h3[(size_t)row * 10 + j0 + jj] = v;
        ss += v * v;
    }
    red[r][g] = ss;
    __syncthreads();
    if (t < 64) {
        float s = red[t][0] + red[t][1] + red[t][2] + red[t][3];  // fixed order
        norms3[row0 + t] = (float)sqrt((double)s);
    }
}

// ============ layer 4: h4 = (h3*m3) @ W4[10x10] + b4 (no relu), norms ============
__global__ __launch_bounds__(256)
void layer4_kernel(const float* __restrict__ h3, const float* __restrict__ W4,
                   const float* __restrict__ b4, const float* __restrict__ mask3,
                   float* __restrict__ h4, float* __restrict__ norms4)
{
    __shared__ float w[100];
    __shared__ float bb[10];
    const int t = threadIdx.x;
    if (t < 100) w[t] = W4[t];
    if (t < 10)  bb[t] = b4[t];
    __syncthreads();

    const int row = blockIdx.x * 256 + t;
    const float m = mask3[row];
    const float* hr = h3 + (size_t)row * 10;
    float v[10];
    #pragma unroll
    for (int k = 0; k < 10; ++k) v[k] = hr[k] * m;

    float s = 0.0f;
    #pragma unroll
    for (int j = 0; j < 10; ++j) {
        float a = 0.0f;
        #pragma unroll
        for (int k = 0; k < 10; ++k) a = fmaf(v[k], w[k*10 + j], a);
        a += bb[j];                     // dot then +bias (matches ref)
        h4[(size_t)row * 10 + j] = a;
        s = fmaf(a, a, s);
    }
    norms4[row] = (float)sqrt((double)s);
}

// ============ final: out = softmax(h4 * m4) ============
__global__ __launch_bounds__(256)
void softmax_kernel(const float* __restrict__ h4, const float* __restrict__ mask4,
                    float* __restrict__ out)
{
    const int t   = threadIdx.x;
    const int row = blockIdx.x * 256 + t;
    const float m = mask4[row];
    const float* hr = h4 + (size_t)row * 10;
    float v[10];
    #pragma unroll
    for (int k = 0; k < 10; ++k) v[k] = hr[k] * m;
    float mx = v[0];
    #pragma unroll
    for (int k = 1; k < 10; ++k) mx = fmaxf(mx, v[k]);
    float e[10];
    float s = 0.0f;
    #pragma unroll
    for (int k = 0; k < 10; ++k) { e[k] = expf(v[k] - mx); s += e[k]; }
    const float inv = 1.0f / s;
    #pragma unroll
    for (int k = 0; k < 10; ++k) out[(size_t)row * 10 + k] = e[k] * inv;
}

extern "C" void kernel_launch(void* const* d_in, const int* in_sizes, int n_in,
                              void* d_out, int out_size, void* d_ws, size_t ws_size,
                              hipStream_t stream)
{
    const float* x  = (const float*)d_in[0];
    const float* W1 = (const float*)d_in[1];
    const float* b1 = (const float*)d_in[2];
    const float* W2 = (const float*)d_in[3];
    const float* b2 = (const float*)d_in[4];
    const float* W3 = (const float*)d_in[5];
    const float* b3 = (const float*)d_in[6];
    const float* W4 = (const float*)d_in[7];
    const float* b4 = (const float*)d_in[8];

    float* out = (float*)d_out;                 // [65536,10]
    float* m1  = out + (size_t)BATCH * 10;      // [65536] each
    float* m2  = m1 + BATCH;
    float* m3  = m2 + BATCH;
    float* m4  = m3 + BATCH;

    float* ws    = (float*)d_ws;
    float* h1    = ws;                                  // 65536*512
    float* h2    = h1 + (size_t)BATCH * 512;            // 65536*256
    float* h3    = h2 + (size_t)BATCH * 256;            // 65536*10
    float* h4    = h3 + (size_t)BATCH * 10;             // 65536*10
    float* n1    = h4 + (size_t)BATCH * 10;             // 65536 x4
    float* n2    = n1 + BATCH;
    float* n3    = n2 + BATCH;
    float* n4    = n3 + BATCH;
    float* part  = n4 + BATCH;                          // 4*65536
    float* thr   = part + (size_t)4 * BATCH;            // 4

    // layer 1: x[65536,784] @ W1[784,512]
    gemm_relu_norm<false><<<dim3(256, 4), 256, 0, stream>>>(x, W1, b1, nullptr, h1, part, 512, 784);
    reduce_norms_kernel<<<256, 256, 0, stream>>>(part, n1, 4);
    select_kernel<<<1, 1024, 0, stream>>>(n1, m1, thr + 0);

    // layer 2: (h1*m1)[65536,512] @ W2[512,256]
    gemm_relu_norm<true><<<dim3(256, 2), 256, 0, stream>>>(h1, W2, b2, m1, h2, part, 256, 512);
    reduce_norms_kernel<<<256, 256, 0, stream>>>(part, n2, 2);
    select_kernel<<<1, 1024, 0, stream>>>(n2, m2, thr + 1);

    // layer 3: (h2*m2)[65536,256] @ W3[256,10]
    layer3_kernel<<<1024, 256, 0, stream>>>(h2, W3, b3, m2, h3, n3);
    select_kernel<<<1, 1024, 0, stream>>>(n3, m3, thr + 2);

    // layer 4: (h3*m3)[65536,10] @ W4[10,10] (no relu)
    layer4_kernel<<<256, 256, 0, stream>>>(h3, W4, b4, m3, h4, n4);
    select_kernel<<<1, 1024, 0, stream>>>(n4, m4, thr + 3);

    // softmax(h4*m4)
    softmax_kernel<<<256, 256, 0, stream>>>(h4, m4, out);
}

// Round 3
// 1249.155 us; speedup vs baseline: 8.6284x; 1.0316x over previous
//
#include <hip/hip_runtime.h>
#include <cstdint>
#include <cstddef>

#define BATCH   65536
#define RANK_K  32769   // sorted_desc[32768] == 32769-th largest (1-indexed)

// ============ big GEMM (layers 1&2): C = relu((A*rowmask) @ B + bias), + per-row sum-of-squares partials ============
// BM=256, BN=128, BK=16, 256 threads, 16x8 per thread.
// v4 = v3 (single LDS buffer + Bs XOR bank swizzle) + REGISTER PREFETCH:
//   loads for tile t+1 are issued AFTER the post-staging barrier and BEFORE the
//   FMA block of tile t.  hipcc drains vmcnt(0) at every __syncthreads, so these
//   loads drain at the NEXT barrier, ~10k cycles later -> HBM/L2 latency hidden
//   under compute.  No double buffer, no runtime buffer index, no conditional
//   liveness (last-tile prefetch address is clamped -> harmless re-read) to keep
//   the allocator on the round-0 plan (acc in AGPRs, ~110 arch VGPRs).
// Per-output-element FMA chain order is IDENTICAL to the validated kernel
// (k ascending, single-register chain, bias->relu->square->16-group row
// reduction in same order) -> bit-identical results -> masks cannot flip.
template<bool MASKED>
__global__ __launch_bounds__(256, 2)
void gemm_relu_norm(const float* __restrict__ A, const float* __restrict__ B,
                    const float* __restrict__ bias, const float* __restrict__ mask,
                    float* __restrict__ C, float* __restrict__ normPart,
                    const int N, const int K)
{
    __shared__ float As[16][260];   // [k][row], padded
    __shared__ float Bs[16][128];   // [k][col], granule-swizzled
    __shared__ float red[256][17];  // row-norm partial reduction

    const int t    = threadIdx.x;
    const int tr   = t >> 4;          // 0..15 row group (16 rows each)
    const int tc   = t & 15;          // 0..15 col group (8 cols each)
    const int row0 = blockIdx.x * 256;
    const int col0 = blockIdx.y * 128;

    // A-load: thread t loads row (row0+t), 16 consecutive k per tile (one 64B line)
    const float* Aptr = A + (size_t)(row0 + t) * K;
    // B-load: 16 k-rows x 128 cols; thread: k=t>>4, cols (t&15)*8..+7
    const int bk = t >> 4;
    const int bc = (t & 15) * 8;
    const float* Bptr = B + (size_t)bk * N + col0 + bc;

    // bank swizzle: XOR bit2 of float-offset (16B granule swap) keyed on bit3.
    // Same involution on store and load sides -> data correct.
    const int bsw   = ((tc >> 3) & 1) << 2;
    const int bo_lo = (tc * 8) ^ bsw;
    const int bo_hi = (tc * 8 + 4) ^ bsw;
    const int bs_lo = bc ^ bsw;
    const int bs_hi = (bc + 4) ^ bsw;

    float scale = 1.0f;
    if (MASKED) scale = mask[row0 + t];

    float acc[16][8];
    #pragma unroll
    for (int i = 0; i < 16; ++i)
        #pragma unroll
        for (int j = 0; j < 8; ++j) acc[i][j] = 0.0f;

    // ---- prologue: load tile 0 into registers ----
    float4 a0 = *(const float4*)(Aptr + 0);
    float4 a1 = *(const float4*)(Aptr + 4);
    float4 a2 = *(const float4*)(Aptr + 8);
    float4 a3 = *(const float4*)(Aptr + 12);
    float4 b0 = *(const float4*)(Bptr + 0);
    float4 b1 = *(const float4*)(Bptr + 4);

    for (int k0 = 0; k0 < K; k0 += 16) {
        // ---- stage current tile (regs -> LDS); scale applied here, matches ref ----
        if (MASKED) {
            a0.x *= scale; a0.y *= scale; a0.z *= scale; a0.w *= scale;
            a1.x *= scale; a1.y *= scale; a1.z *= scale; a1.w *= scale;
            a2.x *= scale; a2.y *= scale; a2.z *= scale; a2.w *= scale;
            a3.x *= scale; a3.y *= scale; a3.z *= scale; a3.w *= scale;
        }
        As[ 0][t] = a0.x; As[ 1][t] = a0.y; As[ 2][t] = a0.z; As[ 3][t] = a0.w;
        As[ 4][t] = a1.x; As[ 5][t] = a1.y; As[ 6][t] = a1.z; As[ 7][t] = a1.w;
        As[ 8][t] = a2.x; As[ 9][t] = a2.y; As[10][t] = a2.z; As[11][t] = a2.w;
        As[12][t] = a3.x; As[13][t] = a3.y; As[14][t] = a3.z; As[15][t] = a3.w;
        *(float4*)&Bs[bk][bs_lo] = b0;   // swizzled store (involution with read)
        *(float4*)&Bs[bk][bs_hi] = b1;
        __syncthreads();

        // ---- issue next-tile loads NOW (drain happens at the NEXT barrier) ----
        const int k0n = (k0 + 16 < K) ? (k0 + 16) : k0;   // clamp: last iter re-reads, never stored
        a0 = *(const float4*)(Aptr + k0n);
        a1 = *(const float4*)(Aptr + k0n + 4);
        a2 = *(const float4*)(Aptr + k0n + 8);
        a3 = *(const float4*)(Aptr + k0n + 12);
        b0 = *(const float4*)(Bptr + (size_t)k0n * N);
        b1 = *(const float4*)(Bptr + (size_t)k0n * N + 4);

        // ---- compute current tile from LDS ----
        #pragma unroll
        for (int kk = 0; kk < 16; ++kk) {
            float a_[16], b_[8];
            *(float4*)&a_[0]  = *(const float4*)&As[kk][tr*16];
            *(float4*)&a_[4]  = *(const float4*)&As[kk][tr*16 + 4];
            *(float4*)&a_[8]  = *(const float4*)&As[kk][tr*16 + 8];
            *(float4*)&a_[12] = *(const float4*)&As[kk][tr*16 + 12];
            *(float4*)&b_[0]  = *(const float4*)&Bs[kk][bo_lo];
            *(float4*)&b_[4]  = *(const float4*)&Bs[kk][bo_hi];
            #pragma unroll
            for (int i = 0; i < 16; ++i)
                #pragma unroll
                for (int j = 0; j < 8; ++j)
                    acc[i][j] = fmaf(a_[i], b_[j], acc[i][j]);
        }
        __syncthreads();
    }

    float bv[8];
    #pragma unroll
    for (int j = 0; j < 8; ++j) bv[j] = bias[col0 + tc*8 + j];

    float rowsum[16];
    #pragma unroll
    for (int i = 0; i < 16; ++i) {
        float s = 0.0f;
        #pragma unroll
        for (int j = 0; j < 8; ++j) {
            float v = fmaxf(acc[i][j] + bv[j], 0.0f);   // dot, +bias, relu (matches ref)
            acc[i][j] = v;
            s = fmaf(v, v, s);
        }
        rowsum[i] = s;
    }

    #pragma unroll
    for (int i = 0; i < 16; ++i) {
        const size_t row = (size_t)(row0 + tr*16 + i);
        *(float4*)&C[row * N + col0 + tc*8]     = *(float4*)&acc[i][0];
        *(float4*)&C[row * N + col0 + tc*8 + 4] = *(float4*)&acc[i][4];
    }

    #pragma unroll
    for (int i = 0; i < 16; ++i) red[tr*16 + i][tc] = rowsum[i];
    __syncthreads();
    {
        float s = 0.0f;
        #pragma unroll
        for (int x = 0; x < 16; ++x) s += red[t][x];    // fixed order -> deterministic
        normPart[(size_t)blockIdx.y * BATCH + row0 + t] = s;
    }
}

// ============ deterministic partial-sum -> norm (sqrt in double = correctly-rounded fp32 sqrt) ============
__global__ __launch_bounds__(256)
void reduce_norms_kernel(const float* __restrict__ part, float* __restrict__ norms, const int nPart)
{
    const int i = blockIdx.x * 256 + threadIdx.x;
    float s = 0.0f;
    for (int p = 0; p < nPart; ++p) s += part[(size_t)p * BATCH + i];
    norms[i] = (float)sqrt((double)s);
}

// ============ exact 32769-th-largest via binary search on uint key space (no atomics) ============
__global__ __launch_bounds__(1024)
void select_kernel(const float* __restrict__ norms, float* __restrict__ maskOut,
                   float* __restrict__ thrOut)
{
    __shared__ int wsum[16];

    const int t = threadIdx.x;
    unsigned key[64];
    const float4* n4 = (const float4*)norms;
    #pragma unroll
    for (int i = 0; i < 16; ++i) {
        float4 v = n4[i * 1024 + t];
        key[i*4+0] = __float_as_uint(v.x);
        key[i*4+1] = __float_as_uint(v.y);
        key[i*4+2] = __float_as_uint(v.z);
        key[i*4+3] = __float_as_uint(v.w);      // nonneg floats -> monotone uint order
    }

    // V = min{ T : count(key > T) < RANK_K }  == exact RANK_K-th largest value
    unsigned lo = 0u, hi = 0x7F800000u;
    while (lo < hi) {                            // uniform across all threads
        const unsigned mid = lo + ((hi - lo) >> 1);
        int c = 0;
        #pragma unroll
        for (int i = 0; i < 64; ++i) c += (key[i] > mid) ? 1 : 0;
        #pragma unroll
        for (int off = 32; off > 0; off >>= 1) c += __shfl_down(c, off, 64);
        if ((t & 63) == 0) wsum[t >> 6] = c;
        __syncthreads();
        int total = 0;
        #pragma unroll
        for (int w = 0; w < 16; ++w) total += wsum[w];
        if (total < RANK_K) hi = mid; else lo = mid + 1;
        __syncthreads();
    }

    if (t == 0) thrOut[0] = __uint_as_float(lo);
    float4* m4 = (float4*)maskOut;
    #pragma unroll
    for (int i = 0; i < 16; ++i) {
        float4 m;
        m.x = (key[i*4+0] > lo) ? 1.0f : 0.0f;
        m.y = (key[i*4+1] > lo) ? 1.0f : 0.0f;
        m.z = (key[i*4+2] > lo) ? 1.0f : 0.0f;
        m.w = (key[i*4+3] > lo) ? 1.0f : 0.0f;   // strict > like reference
        m4[i * 1024 + t] = m;
    }
}

// ============ layer 3: h3 = relu((h2*m2) @ W3[256x10] + b3), full row norms ============
__global__ __launch_bounds__(256)
void layer3_kernel(const float* __restrict__ h2, const float* __restrict__ W3,
                   const float* __restrict__ b3, const float* __restrict__ mask2,
                   float* __restrict__ h3, float* __restrict__ norms3)
{
    __shared__ float wT[10][260];   // transposed W3 for b128 broadcast reads
    __shared__ float red[64][5];

    const int t    = threadIdx.x;
    const int r    = t & 63;
    const int g    = t >> 6;          // 0..3 column groups (3,3,3,1)
    const int j0   = g * 3;
    const int nj   = (g == 3) ? 1 : 3;
    const int row0 = blockIdx.x * 64;
    const int row  = row0 + r;

    for (int e = t; e < 2560; e += 256) wT[e % 10][e / 10] = W3[e];
    __syncthreads();

    const float m = mask2[row];
    const float* hrow = h2 + (size_t)row * 256;

    float acc[3] = {0.0f, 0.0f, 0.0f};
    for (int k = 0; k < 256; k += 4) {
        float4 v = *(const float4*)(hrow + k);
        v.x *= m; v.y *= m; v.z *= m; v.w *= m;
        float4 w0 = *(const float4*)&wT[j0][k];
        acc[0] += v.x*w0.x + v.y*w0.y + v.z*w0.z + v.w*w0.w;
        if (nj > 1) {
            float4 w1 = *(const float4*)&wT[j0+1][k];
            acc[1] += v.x*w1.x + v.y*w1.y + v.z*w1.z + v.w*w1.w;
            float4 w2 = *(const float4*)&wT[j0+2][k];
            acc[2] += v.x*w2.x + v.y*w2.y + v.z*w2.z + v.w*w2.w;
        }
    }

    float ss = 0.0f;
    for (int jj = 0; jj < nj; ++jj) {
        float v = fmaxf(acc[jj] + b3[j0 + jj], 0.0f);
        h3[(size_t)row * 10 + j0 + jj] = v;
        ss += v * v;
    }
    red[r][g] = ss;
    __syncthreads();
    if (t < 64) {
        float s = red[t][0] + red[t][1] + red[t][2] + red[t][3];  // fixed order
        norms3[row0 + t] = (float)sqrt((double)s);
    }
}

// ============ layer 4: h4 = (h3*m3) @ W4[10x10] + b4 (no relu), norms ============
__global__ __launch_bounds__(256)
void layer4_kernel(const float* __restrict__ h3, const float* __restrict__ W4,
                   const float* __restrict__ b4, const float* __restrict__ mask3,
                   float* __restrict__ h4, float* __restrict__ norms4)
{
    __shared__ float w[100];
    __shared__ float bb[10];
    const int t = threadIdx.x;
    if (t < 100) w[t] = W4[t];
    if (t < 10)  bb[t] = b4[t];
    __syncthreads();

    const int row = blockIdx.x * 256 + t;
    const float m = mask3[row];
    const float* hr = h3 + (size_t)row * 10;
    float v[10];
    #pragma unroll
    for (int k = 0; k < 10; ++k) v[k] = hr[k] * m;

    float s = 0.0f;
    #pragma unroll
    for (int j = 0; j < 10; ++j) {
        float a = 0.0f;
        #pragma unroll
        for (int k = 0; k < 10; ++k) a = fmaf(v[k], w[k*10 + j], a);
        a += bb[j];                     // dot then +bias (matches ref)
        h4[(size_t)row * 10 + j] = a;
        s = fmaf(a, a, s);
    }
    norms4[row] = (float)sqrt((double)s);
}

// ============ final: out = softmax(h4 * m4) ============
__global__ __launch_bounds__(256)
void softmax_kernel(const float* __restrict__ h4, const float* __restrict__ mask4,
                    float* __restrict__ out)
{
    const int t   = threadIdx.x;
    const int row = blockIdx.x * 256 + t;
    const float m = mask4[row];
    const float* hr = h4 + (size_t)row * 10;
    float v[10];
    #pragma unroll
    for (int k = 0; k < 10; ++k) v[k] = hr[k] * m;
    float mx = v[0];
    #pragma unroll
    for (int k = 1; k < 10; ++k) mx = fmaxf(mx, v[k]);
    float e[10];
    float s = 0.0f;
    #pragma unroll
    for (int k = 0; k < 10; ++k) { e[k] = expf(v[k] - mx); s += e[k]; }
    const float inv = 1.0f / s;
    #pragma unroll
    for (int k = 0; k < 10; ++k) out[(size_t)row * 10 + k] = e[k] * inv;
}

extern "C" void kernel_launch(void* const* d_in, const int* in_sizes, int n_in,
                              void* d_out, int out_size, void* d_ws, size_t ws_size,
                              hipStream_t stream)
{
    const float* x  = (const float*)d_in[0];
    const float* W1 = (const float*)d_in[1];
    const float* b1 = (const float*)d_in[2];
    const float* W2 = (const float*)d_in[3];
    const float* b2 = (const float*)d_in[4];
    const float* W3 = (const float*)d_in[5];
    const float* b3 = (const float*)d_in[6];
    const float* W4 = (const float*)d_in[7];
    const float* b4 = (const float*)d_in[8];

    float* out = (float*)d_out;                 // [65536,10]
    float* m1  = out + (size_t)BATCH * 10;      // [65536] each
    float* m2  = m1 + BATCH;
    float* m3  = m2 + BATCH;
    float* m4  = m3 + BATCH;

    float* ws    = (float*)d_ws;
    float* h1    = ws;                                  // 65536*512
    float* h2    = h1 + (size_t)BATCH * 512;            // 65536*256
    float* h3    = h2 + (size_t)BATCH * 256;            // 65536*10
    float* h4    = h3 + (size_t)BATCH * 10;             // 65536*10
    float* n1    = h4 + (size_t)BATCH * 10;             // 65536 x4
    float* n2    = n1 + BATCH;
    float* n3    = n2 + BATCH;
    float* n4    = n3 + BATCH;
    float* part  = n4 + BATCH;                          // 4*65536
    float* thr   = part + (size_t)4 * BATCH;            // 4

    // layer 1: x[65536,784] @ W1[784,512]
    gemm_relu_norm<false><<<dim3(256, 4), 256, 0, stream>>>(x, W1, b1, nullptr, h1, part, 512, 784);
    reduce_norms_kernel<<<256, 256, 0, stream>>>(part, n1, 4);
    select_kernel<<<1, 1024, 0, stream>>>(n1, m1, thr + 0);

    // layer 2: (h1*m1)[65536,512] @ W2[512,256]
    gemm_relu_norm<true><<<dim3(256, 2), 256, 0, stream>>>(h1, W2, b2, m1, h2, part, 256, 512);
    reduce_norms_kernel<<<256, 256, 0, stream>>>(part, n2, 2);
    select_kernel<<<1, 1024, 0, stream>>>(n2, m2, thr + 1);

    // layer 3: (h2*m2)[65536,256] @ W3[256,10]
    layer3_kernel<<<1024, 256, 0, stream>>>(h2, W3, b3, m2, h3, n3);
    select_kernel<<<1, 1024, 0, stream>>>(n3, m3, thr + 2);

    // layer 4: (h3*m3)[65536,10] @ W4[10,10] (no relu)
    layer4_kernel<<<256, 256, 0, stream>>>(h3, W4, b4, m3, h4, n4);
    select_kernel<<<1, 1024, 0, stream>>>(n4, m4, thr + 3);

    // softmax(h4*m4)
    softmax_kernel<<<256, 256, 0, stream>>>(h4, m4, out);
}